// Round 3
// baseline (972.631 us; speedup 1.0000x reference)
//
#include <hip/hip_runtime.h>
#include <hip/hip_bf16.h>
#include <math.h>

#define NRES 768
#define C1 384
#define C2 128
#define NH 12

// ws float offsets
#define OFF_QS   0          // 768*192
#define OFF_KS   147456
#define OFF_VS   294912
#define OFF_QPT  442368     // 768*144
#define OFF_KPT  552960
#define OFF_VPT  663552     // 768*288
#define OFF_FA   884736     // 768*2112
#define OFF_RAW  OFF_FA     // raw projections aliased into fa region (consumed by k1b before k2 writes fa)

__device__ __forceinline__ float dot4(float4 a, float4 b) {
    return fmaf(a.x, b.x, fmaf(a.y, b.y, fmaf(a.z, b.z, a.w * b.w)));
}

static constexpr float SCALAR_W = 0.14433756729740643f; // sqrt(1/48)
static constexpr float POINT_W  = 0.13608276348795434f; // sqrt(1/54)
static constexpr float W2D_W    = 0.57735026918962576f; // sqrt(1/3)

__device__ __forceinline__ void wsel(int o,
    const float* w_qs, const float* b_qs, const float* w_kvs, const float* b_kvs,
    const float* w_qp, const float* b_qp, const float* w_kvp, const float* b_kvp,
    const float** row, float* bias)
{
    if (o < 192)      { *row = w_qs  + (size_t)o * C1;         *bias = b_qs[o]; }
    else if (o < 576) { *row = w_kvs + (size_t)(o - 192) * C1; *bias = b_kvs[o - 192]; }
    else if (o < 720) { *row = w_qp  + (size_t)(o - 576) * C1; *bias = b_qp[o - 576]; }
    else              { *row = w_kvp + (size_t)(o - 720) * C1; *bias = b_kvp[o - 720]; }
}

// ---------------------------------------------------------------------------
// K1: raw = in1d @ W_all.T + b_all  (768 x 1152, K=384), tiled GEMM.
// ---------------------------------------------------------------------------
__global__ __launch_bounds__(256) void k1_gemm(
    const float* __restrict__ in1d,
    const float* __restrict__ w_qs, const float* __restrict__ b_qs,
    const float* __restrict__ w_kvs, const float* __restrict__ b_kvs,
    const float* __restrict__ w_qp, const float* __restrict__ b_qp,
    const float* __restrict__ w_kvp, const float* __restrict__ b_kvp,
    float* __restrict__ ws)
{
    __shared__ __align__(16) float ASt[32][68];
    __shared__ __align__(16) float WSt[32][68];
    const int t = threadIdx.x;
    const int n0 = blockIdx.x * 64;
    const int o0 = blockIdx.y * 64;
    const int tx = t & 15, ty = t >> 4;
    float acc[4][4];
    #pragma unroll
    for (int r = 0; r < 4; ++r)
        #pragma unroll
        for (int c = 0; c < 4; ++c) acc[r][c] = 0.f;

    for (int k0 = 0; k0 < C1; k0 += 32) {
        __syncthreads();
        #pragma unroll
        for (int s = 0; s < 2; ++s) {
            int q = t + 256 * s;
            int row = q >> 3, kq = (q & 7) * 4;
            float4 a4 = *(const float4*)&in1d[(size_t)(n0 + row) * C1 + k0 + kq];
            ASt[kq + 0][row] = a4.x; ASt[kq + 1][row] = a4.y;
            ASt[kq + 2][row] = a4.z; ASt[kq + 3][row] = a4.w;
            const float* wr; float bb;
            wsel(o0 + row, w_qs, b_qs, w_kvs, b_kvs, w_qp, b_qp, w_kvp, b_kvp, &wr, &bb);
            float4 w4 = *(const float4*)&wr[k0 + kq];
            WSt[kq + 0][row] = w4.x; WSt[kq + 1][row] = w4.y;
            WSt[kq + 2][row] = w4.z; WSt[kq + 3][row] = w4.w;
        }
        __syncthreads();
        #pragma unroll
        for (int k = 0; k < 32; ++k) {
            float4 a4 = *(const float4*)&ASt[k][ty * 4];
            float4 w4 = *(const float4*)&WSt[k][tx * 4];
            float av[4] = {a4.x, a4.y, a4.z, a4.w};
            float wv[4] = {w4.x, w4.y, w4.z, w4.w};
            #pragma unroll
            for (int r = 0; r < 4; ++r)
                #pragma unroll
                for (int c = 0; c < 4; ++c)
                    acc[r][c] = fmaf(av[r], wv[c], acc[r][c]);
        }
    }
    float bias[4];
    #pragma unroll
    for (int c = 0; c < 4; ++c) {
        const float* dummy;
        wsel(o0 + tx * 4 + c, w_qs, b_qs, w_kvs, b_kvs, w_qp, b_qp, w_kvp, b_kvp, &dummy, &bias[c]);
    }
    float* raw = ws + OFF_RAW;
    #pragma unroll
    for (int r = 0; r < 4; ++r) {
        int n = n0 + ty * 4 + r;
        *(float4*)&raw[(size_t)n * 1152 + o0 + tx * 4] =
            make_float4(acc[r][0] + bias[0], acc[r][1] + bias[1],
                        acc[r][2] + bias[2], acc[r][3] + bias[3]);
    }
}

// ---------------------------------------------------------------------------
// K1b: scatter raw projections into qs/ks/vs and apply global frame to points.
// ---------------------------------------------------------------------------
__global__ __launch_bounds__(256) void k1b_scatter(
    const float* __restrict__ rot, const float* __restrict__ trans,
    float* __restrict__ ws)
{
    __shared__ __align__(16) float rawS[1152];
    const int t = threadIdx.x;
    const int i = blockIdx.x;
    const float* raw = ws + OFF_RAW + (size_t)i * 1152;
    for (int q = t; q < 288; q += 256) *(float4*)&rawS[q * 4] = *(const float4*)&raw[q * 4];
    __syncthreads();
    float* qs  = ws + OFF_QS;  float* ks  = ws + OFF_KS;  float* vs  = ws + OFF_VS;
    float* qpt = ws + OFF_QPT; float* kpt = ws + OFF_KPT; float* vpt = ws + OFF_VPT;

    for (int o = t; o < 576; o += 256) {
        float v = rawS[o];
        if (o < 192) {
            qs[(size_t)i * 192 + o] = v * SCALAR_W;
        } else {
            int idx = o - 192, h = idx >> 5, d = idx & 31;
            if (d < 16) ks[(size_t)i * 192 + h * 16 + d] = v;
            else        vs[(size_t)i * 192 + h * 16 + (d - 16)] = v;
        }
    }
    if (t < 192) {
        int m = t;
        float x0, x1, x2;
        if (m < 48) { x0 = rawS[576 + m]; x1 = rawS[624 + m]; x2 = rawS[672 + m]; }
        else { int mm = m - 48; x0 = rawS[720 + mm]; x1 = rawS[864 + mm]; x2 = rawS[1008 + mm]; }
        float g[3];
        #pragma unroll
        for (int ii = 0; ii < 3; ++ii)
            g[ii] = rot[i * 9 + ii * 3 + 0] * x0 + rot[i * 9 + ii * 3 + 1] * x1 +
                    rot[i * 9 + ii * 3 + 2] * x2 + trans[i * 3 + ii];
        if (m < 48) {
            #pragma unroll
            for (int ii = 0; ii < 3; ++ii) qpt[(size_t)i * 144 + 3 * m + ii] = g[ii];
        } else {
            int mm = m - 48, h = mm / 12, pp = mm % 12;
            if (pp < 4) {
                #pragma unroll
                for (int ii = 0; ii < 3; ++ii) kpt[(size_t)i * 144 + h * 12 + pp * 3 + ii] = g[ii];
            } else {
                #pragma unroll
                for (int ii = 0; ii < 3; ++ii) vpt[(size_t)i * 288 + h * 24 + (pp - 4) * 3 + ii] = g[ii];
            }
        }
    }
}

// ---------------------------------------------------------------------------
// K2: fused single-pass online-softmax IPA row kernel. One block per i.
// 12 tiles of 64 j-rows. Per tile: stage (prefetched regs)->LDS, logits from
// LDS with wave-per-3-heads (uniform w2d -> scalar loads), in-register online
// softmax, apply with next-tile prefetch hidden under the FMA work.
// ---------------------------------------------------------------------------
#define TJ2 64
__global__ __launch_bounds__(256) void k2_attn(
    const float* __restrict__ in2d,
    const float* __restrict__ mask,
    const float* __restrict__ rot, const float* __restrict__ trans,
    const float* __restrict__ tpw,
    const float* __restrict__ w2d, const float* __restrict__ b2d,
    float* __restrict__ ws)
{
    __shared__ __align__(16) float tileS[64][132];  // 33792 B, stride 132 -> 2-way write / cheap read conflicts
    __shared__ __align__(16) float P[NH][68];       // per-tile exp weights
    __shared__ __align__(16) float qsS[192];
    __shared__ __align__(16) float qptS[144];
    __shared__ float qnS[NH], phS[NH], bbS[NH], mS[NH], lS[NH], aS[NH];
    __shared__ float rpgS[288];
    const int t = threadIdx.x;
    const int i = blockIdx.x;

    const float* qs  = ws + OFF_QS;  const float* ks  = ws + OFF_KS;  const float* vs = ws + OFF_VS;
    const float* qpt = ws + OFF_QPT; const float* kpt = ws + OFF_KPT; const float* vpt = ws + OFF_VPT;

    if (t < 48) *(float4*)&qsS[t * 4] = *(const float4*)&qs[(size_t)i * 192 + t * 4];
    else if (t >= 64 && t < 100) { int u = t - 64; *(float4*)&qptS[u * 4] = *(const float4*)&qpt[(size_t)i * 144 + u * 4]; }
    __syncthreads();
    if (t < NH) {
        float s = 0.f;
        #pragma unroll
        for (int e = 0; e < 12; ++e) { float x = qptS[t * 12 + e]; s += x * x; }
        qnS[t] = s;
        phS[t] = -0.5f * POINT_W * logf(1.f + __expf(tpw[t]));
        bbS[t] = W2D_W * b2d[t];
        mS[t] = -1e30f;
        lS[t] = 0.f;
    }
    const float mi = mask[i];

    // roles
    const int jrow = t >> 2, p = t & 3;                 // staging/prefetch mapping
    const int lane = t & 63;
    const int wv = __builtin_amdgcn_readfirstlane(t >> 6);
    const int h0w = wv * 3;                             // this wave's 3 heads (logit phase)
    const bool isR2 = (t < 192);
    int h0p = 0, h1p = 0, c4 = 0, o0 = 0, vh = 0;
    const float* vbase = nullptr; int vstride = 0; bool vact = false;
    if (isR2) { h0p = (t >> 5) * 2; h1p = h0p + 1; c4 = t & 31; }
    else {
        int u = t - 192; o0 = u * 8; vact = (u < 60);
        if (vact) {
            if (o0 < 192) { vh = o0 >> 4; vbase = vs + o0; vstride = 192; }
            else { int q0 = o0 - 192; vh = q0 / 24; vbase = vpt + q0; vstride = 288; }
        }
    }

    float ra[4] = {0.f, 0.f, 0.f, 0.f};
    float rb[4] = {0.f, 0.f, 0.f, 0.f};

    // initial prefetch of tile 0 (row jrow, column chunk p*32)
    float4 r[8];
    {
        const float* nr = in2d + ((size_t)i * NRES + jrow) * C2 + p * 32;
        #pragma unroll
        for (int k = 0; k < 8; ++k) r[k] = *(const float4*)&nr[k * 4];
    }

    for (int tile = 0; tile < 12; ++tile) {
        const int j0 = tile * TJ2;
        __syncthreads();    // B1: prev apply done with tileS & P (also covers setup on tile 0)
        // ---- C: stage prefetched regs into LDS ----
        #pragma unroll
        for (int k = 0; k < 8; ++k) *(float4*)&tileS[jrow][p * 32 + k * 4] = r[k];
        __syncthreads();    // B2: tile visible
        // ---- A+D: logits + online softmax, wave handles heads h0w..h0w+2 for j=lane ----
        {
            const int j = j0 + lane;
            const float* ksr  = ks  + (size_t)j * 192 + h0w * 16;   // 48 contiguous floats
            const float* kptr = kpt + (size_t)j * 144 + h0w * 12;   // 36 contiguous floats
            const float msub = -100000.0f * (1.0f - mi * mask[j]);
            const float* wrow = w2d + h0w * C2;                      // wave-uniform -> scalar loads
            float a0 = 0.f, a1 = 0.f, a2 = 0.f;
            #pragma unroll
            for (int c = 0; c < 32; ++c) {
                float4 v4 = *(const float4*)&tileS[lane][c * 4];
                a0 += dot4(v4, *(const float4*)&wrow[c * 4]);
                a1 += dot4(v4, *(const float4*)&wrow[C2 + c * 4]);
                a2 += dot4(v4, *(const float4*)&wrow[2 * C2 + c * 4]);
            }
            float lg[3];
            #pragma unroll
            for (int e = 0; e < 3; ++e) {
                int h = h0w + e;
                float sq = 0.f;
                #pragma unroll
                for (int d4 = 0; d4 < 4; ++d4)
                    sq += dot4(*(const float4*)&qsS[h * 16 + d4 * 4],
                               *(const float4*)&ksr[e * 16 + d4 * 4]);
                float qk = 0.f, kk = 0.f;
                #pragma unroll
                for (int e4 = 0; e4 < 3; ++e4) {
                    float4 kp4 = *(const float4*)&kptr[e * 12 + e4 * 4];
                    float4 qp4 = *(const float4*)&qptS[h * 12 + e4 * 4];
                    qk += dot4(qp4, kp4);
                    kk += dot4(kp4, kp4);
                }
                float a2d = (e == 0) ? a0 : ((e == 1) ? a1 : a2);
                lg[e] = sq + phS[h] * (qnS[h] + kk - 2.f * qk) + W2D_W * a2d + bbS[h] + msub;
            }
            #pragma unroll
            for (int e = 0; e < 3; ++e) {
                int h = h0w + e;
                float mt = lg[e];
                #pragma unroll
                for (int off = 32; off > 0; off >>= 1) mt = fmaxf(mt, __shfl_xor(mt, off));
                float mold = mS[h];
                float mnew = fmaxf(mold, mt);
                float ev = __expf(lg[e] - mnew);
                P[h][lane] = ev;
                float s = ev;
                #pragma unroll
                for (int off = 32; off > 0; off >>= 1) s += __shfl_xor(s, off);
                if (lane == 0) {
                    float al = __expf(mold - mnew);
                    aS[h] = al;
                    lS[h] = lS[h] * al + s;
                    mS[h] = mnew;
                }
            }
        }
        __syncthreads();    // B3: P + aS ready
        // ---- E: rescale, prefetch next tile, apply ----
        {
            int nt = (tile < 11) ? tile + 1 : 11;
            const float* nr = in2d + ((size_t)i * NRES + nt * TJ2 + jrow) * C2 + p * 32;
            if (isR2) {
                float al0 = aS[h0p], al1 = aS[h1p];
                #pragma unroll
                for (int k = 0; k < 4; ++k) { ra[k] *= al0; rb[k] *= al1; }
                #pragma unroll
                for (int k = 0; k < 8; ++k) r[k] = *(const float4*)&nr[k * 4];
                for (int jj = 0; jj < 64; jj += 4) {
                    float4 p0 = *(const float4*)&P[h0p][jj];
                    float4 p1 = *(const float4*)&P[h1p][jj];
                    float w0[4] = {p0.x, p0.y, p0.z, p0.w};
                    float w1[4] = {p1.x, p1.y, p1.z, p1.w};
                    #pragma unroll
                    for (int k = 0; k < 4; ++k) {
                        float4 v4 = *(const float4*)&tileS[jj + k][c4 * 4];
                        ra[0] = fmaf(w0[k], v4.x, ra[0]); ra[1] = fmaf(w0[k], v4.y, ra[1]);
                        ra[2] = fmaf(w0[k], v4.z, ra[2]); ra[3] = fmaf(w0[k], v4.w, ra[3]);
                        rb[0] = fmaf(w1[k], v4.x, rb[0]); rb[1] = fmaf(w1[k], v4.y, rb[1]);
                        rb[2] = fmaf(w1[k], v4.z, rb[2]); rb[3] = fmaf(w1[k], v4.w, rb[3]);
                    }
                }
            } else {
                #pragma unroll
                for (int k = 0; k < 8; ++k) r[k] = *(const float4*)&nr[k * 4];
                if (vact) {
                    float al = aS[vh];
                    #pragma unroll
                    for (int k = 0; k < 4; ++k) { ra[k] *= al; rb[k] *= al; }
                    for (int jj = 0; jj < 64; jj += 4) {
                        int jg = j0 + jj;
                        float4 pv = *(const float4*)&P[vh][jj];
                        float w[4] = {pv.x, pv.y, pv.z, pv.w};
                        #pragma unroll
                        for (int k = 0; k < 4; ++k) {
                            float4 va = *(const float4*)&vbase[(size_t)(jg + k) * vstride];
                            float4 vb = *(const float4*)&vbase[(size_t)(jg + k) * vstride + 4];
                            ra[0] = fmaf(w[k], va.x, ra[0]); ra[1] = fmaf(w[k], va.y, ra[1]);
                            ra[2] = fmaf(w[k], va.z, ra[2]); ra[3] = fmaf(w[k], va.w, ra[3]);
                            rb[0] = fmaf(w[k], vb.x, rb[0]); rb[1] = fmaf(w[k], vb.y, rb[1]);
                            rb[2] = fmaf(w[k], vb.z, rb[2]); rb[3] = fmaf(w[k], vb.w, rb[3]);
                        }
                    }
                }
            }
        }
    }
    // ---- finalize ----
    float* fa = ws + OFF_FA + (size_t)i * 2112;
    if (isR2) {
        float n0v = 1.f / lS[h0p], n1v = 1.f / lS[h1p];
        *(float4*)&fa[576 + h0p * 128 + c4 * 4] = make_float4(ra[0] * n0v, ra[1] * n0v, ra[2] * n0v, ra[3] * n0v);
        *(float4*)&fa[576 + h1p * 128 + c4 * 4] = make_float4(rb[0] * n1v, rb[1] * n1v, rb[2] * n1v, rb[3] * n1v);
    } else if (vact) {
        float nv = 1.f / lS[vh];
        if (o0 < 192) {
            *(float4*)&fa[o0]     = make_float4(ra[0] * nv, ra[1] * nv, ra[2] * nv, ra[3] * nv);
            *(float4*)&fa[o0 + 4] = make_float4(rb[0] * nv, rb[1] * nv, rb[2] * nv, rb[3] * nv);
        } else {
            int q0 = o0 - 192;
            *(float4*)&rpgS[q0]     = make_float4(ra[0] * nv, ra[1] * nv, ra[2] * nv, ra[3] * nv);
            *(float4*)&rpgS[q0 + 4] = make_float4(rb[0] * nv, rb[1] * nv, rb[2] * nv, rb[3] * nv);
        }
    }
    __syncthreads();
    if (t < 96) {
        int h = t >> 3, pp = t & 7;
        float rv[3];
        #pragma unroll
        for (int c = 0; c < 3; ++c) rv[c] = rpgS[h * 24 + pp * 3 + c] - trans[i * 3 + c];
        float l0 = rot[i * 9 + 0] * rv[0] + rot[i * 9 + 3] * rv[1] + rot[i * 9 + 6] * rv[2];
        float l1 = rot[i * 9 + 1] * rv[0] + rot[i * 9 + 4] * rv[1] + rot[i * 9 + 7] * rv[2];
        float l2 = rot[i * 9 + 2] * rv[0] + rot[i * 9 + 5] * rv[1] + rot[i * 9 + 8] * rv[2];
        float dd = sqrtf(1e-8f + l0 * l0 + l1 * l1 + l2 * l2);
        fa[192 + t] = l0;
        fa[288 + t] = l1;
        fa[384 + t] = l2;
        fa[480 + t] = dd;
    }
}

// ---------------------------------------------------------------------------
// K3: out = final_act @ w_out.T + b_out.  32x32 tiles, 2x2 micro-tile,
// register-prefetch software pipeline to hide L3 latency.
// ---------------------------------------------------------------------------
__global__ __launch_bounds__(256) void k3_out(
    const float* __restrict__ w_out, const float* __restrict__ b_out,
    const float* __restrict__ ws, float* __restrict__ out)
{
    __shared__ __align__(16) float ASt[32][34];
    __shared__ __align__(16) float WSt[32][34];
    const int t = threadIdx.x;
    const int i0 = blockIdx.x * 32;
    const int o0 = blockIdx.y * 32;
    const float* fa = ws + OFF_FA;
    int tx = t & 15, ty = t >> 4;
    float acc00 = 0.f, acc01 = 0.f, acc10 = 0.f, acc11 = 0.f;
    int r = t >> 3, kq = (t & 7) * 4;
    const float* arow = fa + (size_t)(i0 + r) * 2112 + kq;
    const float* wrow = w_out + (size_t)(o0 + r) * 2112 + kq;
    float4 a4 = *(const float4*)&arow[0];
    float4 w4 = *(const float4*)&wrow[0];

    for (int k0 = 0; k0 < 2112; k0 += 32) {
        ASt[kq + 0][r] = a4.x; ASt[kq + 1][r] = a4.y; ASt[kq + 2][r] = a4.z; ASt[kq + 3][r] = a4.w;
        WSt[kq + 0][r] = w4.x; WSt[kq + 1][r] = w4.y; WSt[kq + 2][r] = w4.z; WSt[kq + 3][r] = w4.w;
        __syncthreads();
        if (k0 + 32 < 2112) {
            a4 = *(const float4*)&arow[k0 + 32];
            w4 = *(const float4*)&wrow[k0 + 32];
        }
        #pragma unroll
        for (int k = 0; k < 32; ++k) {
            float2 av = *(const float2*)&ASt[k][ty * 2];
            float2 wv = *(const float2*)&WSt[k][tx * 2];
            acc00 = fmaf(av.x, wv.x, acc00);
            acc01 = fmaf(av.x, wv.y, acc01);
            acc10 = fmaf(av.y, wv.x, acc10);
            acc11 = fmaf(av.y, wv.y, acc11);
        }
        __syncthreads();
    }
    int oi = i0 + ty * 2, oo = o0 + tx * 2;
    out[(size_t)oi * 384 + oo]           = acc00 + b_out[oo];
    out[(size_t)oi * 384 + oo + 1]       = acc01 + b_out[oo + 1];
    out[(size_t)(oi + 1) * 384 + oo]     = acc10 + b_out[oo];
    out[(size_t)(oi + 1) * 384 + oo + 1] = acc11 + b_out[oo + 1];
}

extern "C" void kernel_launch(void* const* d_in, const int* in_sizes, int n_in,
                              void* d_out, int out_size, void* d_ws, size_t ws_size,
                              hipStream_t stream) {
    const float* in1d  = (const float*)d_in[0];
    const float* in2d  = (const float*)d_in[1];
    const float* mask  = (const float*)d_in[2];
    const float* rot   = (const float*)d_in[3];
    const float* trans = (const float*)d_in[4];
    const float* w_qs  = (const float*)d_in[5];
    const float* b_qs  = (const float*)d_in[6];
    const float* w_kvs = (const float*)d_in[7];
    const float* b_kvs = (const float*)d_in[8];
    const float* w_qp  = (const float*)d_in[9];
    const float* b_qp  = (const float*)d_in[10];
    const float* w_kvp = (const float*)d_in[11];
    const float* b_kvp = (const float*)d_in[12];
    const float* tpw   = (const float*)d_in[13];
    const float* w2d   = (const float*)d_in[14];
    const float* b2d   = (const float*)d_in[15];
    const float* w_out = (const float*)d_in[16];
    const float* b_out = (const float*)d_in[17];
    float* ws  = (float*)d_ws;
    float* out = (float*)d_out;

    hipLaunchKernelGGL(k1_gemm, dim3(12, 18), dim3(256), 0, stream,
                       in1d, w_qs, b_qs, w_kvs, b_kvs, w_qp, b_qp, w_kvp, b_kvp, ws);
    hipLaunchKernelGGL(k1b_scatter, dim3(768), dim3(256), 0, stream,
                       rot, trans, ws);
    hipLaunchKernelGGL(k2_attn, dim3(768), dim3(256), 0, stream,
                       in2d, mask, rot, trans, tpw, w2d, b2d, ws);
    hipLaunchKernelGGL(k3_out, dim3(24, 12), dim3(256), 0, stream,
                       w_out, b_out, ws, out);
}